// Round 5
// baseline (608.096 us; speedup 1.0000x reference)
//
#include <hip/hip_runtime.h>

// Entropic Sinkhorn EMD, B=2, N=4096, D=3, EPS=0.1, 20 iters.
// Round-5: round-4's SGPR-row-constant structure, PLUS:
//  - staggered j-streaming (phase = (blockIdx.x>>3)&7) to kill L2 channel
//    hot-spotting (all blocks previously read identical lines in lockstep)
//  - RPB 8->16, NT 256->512: 96 VALU instr per float4 load, 32 MB L2/sweep
//  - fully unrolled k-loop (8 iters) for load-ahead; VGPR cap 128 (4 w/SIMD)

#define N   4096
#define NT  512
#define RPB 16     // rows per block -> grid.x = 256, 512 blocks total
#define KIT (N / NT)   // 8 j-chunks per lane

constexpr float EPS_F  = 0.1f;
constexpr float SHIFT  = 60.0f;
constexpr float LOG_A  = -8.317766166719343f;   // -log(4096)
constexpr float L2E    = 1.4426950408889634f;   // log2(e)
constexpr float C10L   = 14.426950408889634f;   // 10*log2(e)
constexpr float C20L   = 28.853900817779268f;   // 20*log2(e)
constexpr float SHIFTL = 86.56170245333781f;    // SHIFT*log2(e)
constexpr float NLN2T  = -0.06931471805599453f; // -ln2/10
constexpr float LN2    = 0.6931471805599453f;

__device__ __forceinline__ float rfl(float x) {
    return __int_as_float(__builtin_amdgcn_readfirstlane(__float_as_int(x)));
}

// Pack {x,y,z, h2(g=0) = SHIFTL - 10L|p|^2}; wBase = -10L|p|^2; zero f,g,out.
__global__ __launch_bounds__(256) void prep_kernel(
    const float* __restrict__ gen, const float* __restrict__ gt,
    float4* __restrict__ genPack, float4* __restrict__ gtPack,
    float* __restrict__ wBaseGen, float* __restrict__ wBaseGt,
    float* __restrict__ fg, float* __restrict__ out)
{
    int t = blockIdx.x * 256 + threadIdx.x;   // 0 .. 16383
    int cloud = t >> 13;
    int idx   = t & 8191;                     // b*N + j
    const float* src = cloud ? gt : gen;
    float x = src[idx * 3 + 0];
    float y = src[idx * 3 + 1];
    float z = src[idx * 3 + 2];
    float nb = -C10L * fmaf(z, z, fmaf(y, y, x * x));   // -10L|p|^2
    (cloud ? gtPack : genPack)[idx] = make_float4(x, y, z, SHIFTL + nb);
    (cloud ? wBaseGt : wBaseGen)[idx] = nb;
    fg[t] = 0.0f;                             // f[2][N] then g[2][N]
    if (t == 0) out[0] = 0.0f;
}

// Half-sweep. 16 rows/block with constants pinned in SGPRs; columns streamed
// one float4/j from L2 with per-block phase stagger. Epilogue writes the new
// dual and refreshes packRow.w = h2 so the next sweep reads one load per j.
__global__ __launch_bounds__(NT, 4) void sweep_kernel(
    float4*       __restrict__ packRow,   // [2][N]
    const float4* __restrict__ packCol,   // [2][N]
    const float*  __restrict__ wBaseRow,  // [2][N]
    float*        __restrict__ dualRaw)   // [2][N]
{
    const int b   = blockIdx.y;
    const int tid = threadIdx.x;
    const int rowBase = blockIdx.x * RPB;

    float4*      rp = packRow  + (size_t)b * N + rowBase;
    const float* wb = wBaseRow + (size_t)b * N + rowBase;

    float X[RPB], Y[RPB], Z[RPB], S[RPB];
    #pragma unroll
    for (int r = 0; r < RPB; ++r) {
        float4 q = rp[r];
        X[r] = rfl(q.x * C20L);
        Y[r] = rfl(q.y * C20L);
        Z[r] = rfl(q.z * C20L);
        S[r] = rfl(wb[r]);                 // -10L|p_i|^2
    }

    const float4* cp = packCol + (size_t)b * N;
    const int k0 = (blockIdx.x >> 3) & (KIT - 1);   // phase stagger

    float acc[RPB];
    #pragma unroll
    for (int r = 0; r < RPB; ++r) acc[r] = 0.0f;

    #pragma unroll
    for (int kk = 0; kk < KIT; ++kk) {
        const int k = (kk + k0) & (KIT - 1);
        float4 p = cp[tid + NT * k];       // {xj, yj, zj, h2j}
        #pragma unroll
        for (int r = 0; r < RPB; ++r) {
            float t = fmaf(Z[r], p.z, p.w);
            t = fmaf(Y[r], p.y, t);
            t = fmaf(X[r], p.x, t);
            acc[r] += exp2f(t + S[r]);
        }
    }

    // Reduce each row-sum across the block.
    #pragma unroll
    for (int r = 0; r < RPB; ++r) {
        float a = acc[r];
        a += __shfl_xor(a, 32);
        a += __shfl_xor(a, 16);
        a += __shfl_xor(a, 8);
        a += __shfl_xor(a, 4);
        a += __shfl_xor(a, 2);
        a += __shfl_xor(a, 1);
        acc[r] = a;
    }
    __shared__ float sred[RPB][8];
    const int wave = tid >> 6, lane = tid & 63;
    if (lane == 0) {
        #pragma unroll
        for (int r = 0; r < RPB; ++r) sred[r][wave] = acc[r];
    }
    __syncthreads();
    if (tid < RPB) {
        float s = 0.f;
        #pragma unroll
        for (int w = 0; w < 8; ++w) s += sred[tid][w];
        float dual = EPS_F * (LOG_A + SHIFT - log2f(s) * LN2);
        dualRaw[(size_t)b * N + rowBase + tid] = dual;
        ((float*)(rp + tid))[3] = fmaf(dual, C10L, SHIFTL + wb[tid]);
    }
}

// loss += 0.5 * sum_ij exp((f_i + g_j - C_ij)/EPS) * C_ij
__global__ __launch_bounds__(NT, 4) void loss_kernel(
    const float4* __restrict__ packGen,   // rows
    const float4* __restrict__ packGt,    // columns
    const float*  __restrict__ wBaseGen,
    const float*  __restrict__ f,
    const float*  __restrict__ g,
    float*        __restrict__ out)
{
    const int b   = blockIdx.y;
    const int tid = threadIdx.x;
    const int rowBase = blockIdx.x * RPB;

    const float4* rp = packGen  + (size_t)b * N + rowBase;
    const float*  wb = wBaseGen + (size_t)b * N + rowBase;
    const float*  fp = f        + (size_t)b * N + rowBase;

    float Ax[RPB], Ay[RPB], Az[RPB], Ri[RPB], F2[RPB];
    #pragma unroll
    for (int r = 0; r < RPB; ++r) {
        float4 q = rp[r];
        Ax[r] = rfl(q.x * -2.0f);
        Ay[r] = rfl(q.y * -2.0f);
        Az[r] = rfl(q.z * -2.0f);
        Ri[r] = rfl(wb[r] * NLN2T);        // |p_i|^2
        F2[r] = rfl(fp[r] * C10L);
    }

    const float4* cp = packGt + (size_t)b * N;
    const float*  gc = g      + (size_t)b * N;
    const int k0 = (blockIdx.x >> 3) & (KIT - 1);

    float acc = 0.0f;
    #pragma unroll
    for (int kk = 0; kk < KIT; ++kk) {
        const int k = (kk + k0) & (KIT - 1);
        float4 p  = cp[tid + NT * k];
        float  gj = gc[tid + NT * k];
        float  G2 = gj * C10L;
        float  rj = fmaf(p.w - SHIFTL, NLN2T, gj);   // |p_j|^2
        #pragma unroll
        for (int r = 0; r < RPB; ++r) {
            float cc = rj + Ri[r];
            cc = fmaf(Az[r], p.z, cc);
            cc = fmaf(Ay[r], p.y, cc);
            cc = fmaf(Ax[r], p.x, cc);
            float arg = fmaf(cc, -C10L, G2 + F2[r]);
            acc = fmaf(exp2f(arg), cc, acc);
        }
    }

    acc += __shfl_xor(acc, 32);
    acc += __shfl_xor(acc, 16);
    acc += __shfl_xor(acc, 8);
    acc += __shfl_xor(acc, 4);
    acc += __shfl_xor(acc, 2);
    acc += __shfl_xor(acc, 1);
    __shared__ float sred[8];
    const int wave = tid >> 6, lane = tid & 63;
    if (lane == 0) sred[wave] = acc;
    __syncthreads();
    if (tid == 0) {
        float t = 0.f;
        #pragma unroll
        for (int w = 0; w < 8; ++w) t += sred[w];
        atomicAdd(out, t * 0.5f);
    }
}

extern "C" void kernel_launch(void* const* d_in, const int* in_sizes, int n_in,
                              void* d_out, int out_size, void* d_ws, size_t ws_size,
                              hipStream_t stream) {
    const float* gen = (const float*)d_in[0];
    const float* gt  = (const float*)d_in[1];
    float* out = (float*)d_out;

    char* ws = (char*)d_ws;
    float4* genPack  = (float4*)ws;                        // 128 KB
    float4* gtPack   = (float4*)(ws + 128 * 1024);         // 128 KB
    float*  wBaseGen = (float*)(ws + 256 * 1024);          // 32 KB
    float*  wBaseGt  = (float*)(ws + 288 * 1024);          // 32 KB
    float*  f        = (float*)(ws + 320 * 1024);          // 32 KB (f then g)
    float*  g        = f + 2 * N;

    prep_kernel<<<dim3(16384 / 256), 256, 0, stream>>>(
        gen, gt, genPack, gtPack, wBaseGen, wBaseGt, f, out);

    const dim3 grid(N / RPB, 2);   // 256 x 2 = 512 blocks
    for (int it = 0; it < 20; ++it) {
        sweep_kernel<<<grid, NT, 0, stream>>>(genPack, gtPack, wBaseGen, f);
        sweep_kernel<<<grid, NT, 0, stream>>>(gtPack, genPack, wBaseGt, g);
    }
    loss_kernel<<<grid, NT, 0, stream>>>(genPack, gtPack, wBaseGen, f, g, out);
}

// Round 6
// 423.930 us; speedup vs baseline: 1.4344x; 1.4344x over previous
//
#include <hip/hip_runtime.h>

// Entropic Sinkhorn EMD, B=2, N=4096, D=3, EPS=0.1, 20 iters.
// Round-6: round-4 structure (SGPR row constants, 1 float4/j stream, pack.w
// carries h2) with ONE change: exp2f() [OCML libm, ~10 instr range-checked]
// -> raw v_exp_f32 via __builtin_amdgcn_exp2f. Sweep time was invariant
// (~13us) across 3 structural rewrites because the libm expansion dominated
// the per-pair instruction stream. Args are range-safe by construction
// (<= +28 log2 units; deep-negative underflows to 0, which is correct).

#define N   4096
#define NT  256
#define RPB 8      // rows per block -> grid.x = 512, 1024 blocks total

constexpr float EPS_F  = 0.1f;
constexpr float SHIFT  = 60.0f;
constexpr float LOG_A  = -8.317766166719343f;   // -log(4096)
constexpr float C10L   = 14.426950408889634f;   // 10*log2(e)
constexpr float C20L   = 28.853900817779268f;   // 20*log2(e)
constexpr float SHIFTL = 86.56170245333781f;    // SHIFT*log2(e)
constexpr float NLN2T  = -0.06931471805599453f; // -ln2/10
constexpr float LN2    = 0.6931471805599453f;

extern "C" __device__ float __ocml_native_exp2_f32(float);

__device__ __forceinline__ float fast_exp2(float x) {
#if __has_builtin(__builtin_amdgcn_exp2f)
    return __builtin_amdgcn_exp2f(x);
#else
    return __ocml_native_exp2_f32(x);
#endif
}

__device__ __forceinline__ float rfl(float x) {
    return __int_as_float(__builtin_amdgcn_readfirstlane(__float_as_int(x)));
}

// Pack {x,y,z, h2(g=0) = SHIFTL - 10L|p|^2}; wBase = -10L|p|^2; zero f,g,out.
__global__ __launch_bounds__(256) void prep_kernel(
    const float* __restrict__ gen, const float* __restrict__ gt,
    float4* __restrict__ genPack, float4* __restrict__ gtPack,
    float* __restrict__ wBaseGen, float* __restrict__ wBaseGt,
    float* __restrict__ fg, float* __restrict__ out)
{
    int t = blockIdx.x * 256 + threadIdx.x;   // 0 .. 16383
    int cloud = t >> 13;
    int idx   = t & 8191;                     // b*N + j
    const float* src = cloud ? gt : gen;
    float x = src[idx * 3 + 0];
    float y = src[idx * 3 + 1];
    float z = src[idx * 3 + 2];
    float nb = -C10L * fmaf(z, z, fmaf(y, y, x * x));   // -10L|p|^2
    (cloud ? gtPack : genPack)[idx] = make_float4(x, y, z, SHIFTL + nb);
    (cloud ? wBaseGt : wBaseGen)[idx] = nb;
    fg[t] = 0.0f;                             // f[2][N] then g[2][N]
    if (t == 0) out[0] = 0.0f;
}

// Half-sweep. 8 rows/block, constants in SGPRs; columns streamed one
// float4/j from L2 (w = current h2 of the column dual). Epilogue writes the
// new dual AND refreshes packRow.w = new h2 for the next sweep.
__global__ __launch_bounds__(NT, 8) void sweep_kernel(
    float4*       __restrict__ packRow,   // [2][N]
    const float4* __restrict__ packCol,   // [2][N]
    const float*  __restrict__ wBaseRow,  // [2][N]
    float*        __restrict__ dualRaw)   // [2][N]
{
    const int b   = blockIdx.y;
    const int tid = threadIdx.x;
    const int rowBase = blockIdx.x * RPB;

    float4*      rp = packRow  + (size_t)b * N + rowBase;
    const float* wb = wBaseRow + (size_t)b * N + rowBase;

    float X[RPB], Y[RPB], Z[RPB], S[RPB];
    #pragma unroll
    for (int r = 0; r < RPB; ++r) {
        float4 q = rp[r];
        X[r] = rfl(q.x * C20L);
        Y[r] = rfl(q.y * C20L);
        Z[r] = rfl(q.z * C20L);
        S[r] = rfl(wb[r]);                 // -10L|p_i|^2
    }

    const float4* cp = packCol + (size_t)b * N;

    float acc[RPB];
    #pragma unroll
    for (int r = 0; r < RPB; ++r) acc[r] = 0.0f;

    #pragma unroll 2
    for (int k = 0; k < N / NT; ++k) {
        float4 p = cp[tid + NT * k];       // {xj, yj, zj, h2j}
        #pragma unroll
        for (int r = 0; r < RPB; ++r) {
            float t = fmaf(Z[r], p.z, p.w);
            t = fmaf(Y[r], p.y, t);
            t = fmaf(X[r], p.x, t);
            acc[r] += fast_exp2(t + S[r]);
        }
    }

    // Reduce each row-sum across the block: wave shuffle + tiny LDS.
    #pragma unroll
    for (int r = 0; r < RPB; ++r) {
        float a = acc[r];
        a += __shfl_xor(a, 32);
        a += __shfl_xor(a, 16);
        a += __shfl_xor(a, 8);
        a += __shfl_xor(a, 4);
        a += __shfl_xor(a, 2);
        a += __shfl_xor(a, 1);
        acc[r] = a;
    }
    __shared__ float sred[RPB][4];
    const int wave = tid >> 6, lane = tid & 63;
    if (lane == 0) {
        #pragma unroll
        for (int r = 0; r < RPB; ++r) sred[r][wave] = acc[r];
    }
    __syncthreads();
    if (tid < RPB) {
        float s = (sred[tid][0] + sred[tid][1]) + (sred[tid][2] + sred[tid][3]);
        float dual = EPS_F * (LOG_A + SHIFT - log2f(s) * LN2);
        dualRaw[(size_t)b * N + rowBase + tid] = dual;
        // refresh h2 for when this cloud serves as the column next sweep
        ((float*)(rp + tid))[3] = fmaf(dual, C10L, SHIFTL + wb[tid]);
    }
}

// loss += 0.5 * sum_ij exp((f_i + g_j - C_ij)/EPS) * C_ij
__global__ __launch_bounds__(NT, 8) void loss_kernel(
    const float4* __restrict__ packGen,   // rows
    const float4* __restrict__ packGt,    // columns
    const float*  __restrict__ wBaseGen,
    const float*  __restrict__ f,
    const float*  __restrict__ g,
    float*        __restrict__ out)
{
    const int b   = blockIdx.y;
    const int tid = threadIdx.x;
    const int rowBase = blockIdx.x * RPB;

    const float4* rp = packGen  + (size_t)b * N + rowBase;
    const float*  wb = wBaseGen + (size_t)b * N + rowBase;
    const float*  fp = f        + (size_t)b * N + rowBase;

    float Ax[RPB], Ay[RPB], Az[RPB], Ri[RPB], F2[RPB];
    #pragma unroll
    for (int r = 0; r < RPB; ++r) {
        float4 q = rp[r];
        Ax[r] = rfl(q.x * -2.0f);
        Ay[r] = rfl(q.y * -2.0f);
        Az[r] = rfl(q.z * -2.0f);
        Ri[r] = rfl(wb[r] * NLN2T);        // |p_i|^2
        F2[r] = rfl(fp[r] * C10L);
    }

    const float4* cp = packGt + (size_t)b * N;
    const float*  gc = g      + (size_t)b * N;

    float acc = 0.0f;
    #pragma unroll 2
    for (int k = 0; k < N / NT; ++k) {
        float4 p  = cp[tid + NT * k];
        float  gj = gc[tid + NT * k];
        float  G2 = gj * C10L;
        float  rj = fmaf(p.w - SHIFTL, NLN2T, gj);   // |p_j|^2
        #pragma unroll
        for (int r = 0; r < RPB; ++r) {
            float cc = rj + Ri[r];
            cc = fmaf(Az[r], p.z, cc);
            cc = fmaf(Ay[r], p.y, cc);
            cc = fmaf(Ax[r], p.x, cc);
            float arg = fmaf(cc, -C10L, G2 + F2[r]);
            acc = fmaf(fast_exp2(arg), cc, acc);
        }
    }

    acc += __shfl_xor(acc, 32);
    acc += __shfl_xor(acc, 16);
    acc += __shfl_xor(acc, 8);
    acc += __shfl_xor(acc, 4);
    acc += __shfl_xor(acc, 2);
    acc += __shfl_xor(acc, 1);
    __shared__ float sred[4];
    const int wave = tid >> 6, lane = tid & 63;
    if (lane == 0) sred[wave] = acc;
    __syncthreads();
    if (tid == 0) {
        float t = (sred[0] + sred[1]) + (sred[2] + sred[3]);
        atomicAdd(out, t * 0.5f);
    }
}

extern "C" void kernel_launch(void* const* d_in, const int* in_sizes, int n_in,
                              void* d_out, int out_size, void* d_ws, size_t ws_size,
                              hipStream_t stream) {
    const float* gen = (const float*)d_in[0];
    const float* gt  = (const float*)d_in[1];
    float* out = (float*)d_out;

    char* ws = (char*)d_ws;
    float4* genPack  = (float4*)ws;                        // 128 KB
    float4* gtPack   = (float4*)(ws + 128 * 1024);         // 128 KB
    float*  wBaseGen = (float*)(ws + 256 * 1024);          // 32 KB
    float*  wBaseGt  = (float*)(ws + 288 * 1024);          // 32 KB
    float*  f        = (float*)(ws + 320 * 1024);          // 32 KB (f then g)
    float*  g        = f + 2 * N;

    prep_kernel<<<dim3(16384 / 256), 256, 0, stream>>>(
        gen, gt, genPack, gtPack, wBaseGen, wBaseGt, f, out);

    const dim3 grid(N / RPB, 2);   // 512 x 2 = 1024 blocks
    for (int it = 0; it < 20; ++it) {
        // f update: rows = gen, cols = gt (reads gtPack.w = h2(g)), writes f + genPack.w
        sweep_kernel<<<grid, NT, 0, stream>>>(genPack, gtPack, wBaseGen, f);
        // g update: rows = gt, cols = gen (reads genPack.w = h2(f)), writes g + gtPack.w
        sweep_kernel<<<grid, NT, 0, stream>>>(gtPack, genPack, wBaseGt, g);
    }
    loss_kernel<<<grid, NT, 0, stream>>>(genPack, gtPack, wBaseGen, f, g, out);
}